// Round 5
// baseline (249.105 us; speedup 1.0000x reference)
//
#include <hip/hip_runtime.h>
#include <stdint.h>

typedef unsigned long long u64;
typedef unsigned int u32;

#define NQ 16384
#define ND 16384
#define KNB 32                  // neighbors emitted per query
#define KK 33                   // need the 33rd-smallest (rank index 32)
#define SPLITS_BASE (NQ * KNB)  // 524288
#define CAP 768                 // LDS candidate pool per query
#define NWQ 4                   // queries (waves) per block
#define G 36
#define G3 (G*G*G)              // 46656 cells
#define FINF (__int_as_float(0x7f800000))

// Exact replication of reference arithmetic (same as passing R1-R4 kernels):
//   q2 = (qx*qx + qy*qy) + qz*qz ; d2 likewise (precomputed per point)
//   dot = fma(qz,z, fma(qy,y, qx*x)) ; sq = (q2+d2) - (dot+dot)
//   key = fmaxf(sq,0) ; k = sqrtf(33rd smallest key) ; accept via ulp cut

__device__ __forceinline__ float wave_max_f(float v) {
    #pragma unroll
    for (int s = 1; s < 64; s <<= 1) v = fmaxf(v, __shfl_xor(v, s, 64));
    return v;
}
__device__ __forceinline__ int wave_sum_i(int v) {
    #pragma unroll
    for (int s = 1; s < 64; s <<= 1) v += __shfl_xor(v, s, 64);
    return v;
}
__device__ __forceinline__ u32 fenc(float f) {
    const u32 u = __float_as_uint(f);
    return (u & 0x80000000u) ? ~u : (u | 0x80000000u);
}
__device__ __forceinline__ float fdec(u32 e) {
    const u32 u = (e & 0x80000000u) ? (e & 0x7fffffffu) : ~e;
    return __uint_as_float(u);
}
__device__ __forceinline__ int iclamp(int v, int lo, int hi) {
    return v < lo ? lo : (v > hi ? hi : v);
}

// min b (float bits) with #{r <= float(b)} >= rank; keys >= 0, pads FINF. (R4-proven)
template<int NR>
__device__ __forceinline__ float bisect_rank(const float (&r)[NR], int rank) {
    u32 lo = 0u, hi = 0x7f800000u;
    #pragma unroll 1
    while (lo < hi) {
        const u32 mid = (lo + hi) >> 1;
        const float pv = __uint_as_float(mid);
        int c = 0;
        #pragma unroll
        for (int j = 0; j < NR; ++j) c += (r[j] <= pv) ? 1 : 0;
        c = wave_sum_i(c);
        if (c >= rank) hi = mid; else lo = mid + 1;
    }
    return __uint_as_float(hi);
}

// Cheap prune (R4-proven): keep key <= M where M = wave_max(lane minima) >= pool 33rd.
__device__ __forceinline__ void pool_prune(float* kp, u32* ip, int& cnt, float& Tk,
                                           int lane, u64 lt) {
    float m = FINF;
    #pragma unroll 1
    for (int j = lane; j < cnt; j += 64) m = fminf(m, kp[j]);
    const float M = wave_max_f(m);
    int nc = 0;
    #pragma unroll 1
    for (int j0 = 0; j0 < cnt; j0 += 64) {
        const int j = j0 + lane;
        const bool val = j < cnt;
        float k = FINF; u32 id = 0;
        if (val) { k = kp[j]; id = ip[j]; }
        const bool keep = val && (k <= M);
        const u64 mask = __ballot(keep);
        if (keep) {
            const int s = nc + (int)__popcll(mask & lt);
            kp[s] = k; ip[s] = id;
        }
        nc += (int)__popcll(mask);
    }
    cnt = nc; Tk = M;
}

// Degenerate-tie path (R4-proven): keep key < v (v = exact 64th) plus <= 64 copies == v.
__device__ __forceinline__ void pool_hard_prune(float* kp, u32* ip, int& cnt,
                                                int lane, u64 lt) {
    float r[12];
    #pragma unroll
    for (int j = 0; j < 12; ++j) {
        const int s = j * 64 + lane;
        r[j] = (s < cnt) ? kp[s] : FINF;
    }
    const float v = bisect_rank(r, 64);
    int nc = 0, eqs = 0;
    #pragma unroll 1
    for (int j0 = 0; j0 < cnt; j0 += 64) {
        const int j = j0 + lane;
        const bool val = j < cnt;
        float k = FINF; u32 id = 0;
        if (val) { k = kp[j]; id = ip[j]; }
        const bool lt_v = val && (k < v);
        const bool eq_v = val && (k == v);
        const u64 mlt = __ballot(lt_v);
        const u64 meq = __ballot(eq_v);
        const int poplt = (int)__popcll(mlt);
        const int popeq = (int)__popcll(meq);
        if (lt_v) { const int s = nc + (int)__popcll(mlt & lt); kp[s] = k; ip[s] = id; }
        if (eq_v) {
            const int pe = (int)__popcll(meq & lt);
            if (eqs + pe < 64) { const int s = nc + poplt + pe; kp[s] = k; ip[s] = id; }
        }
        int kept_eq = popeq;
        if (eqs + popeq > 64) kept_eq = (64 - eqs > 0) ? (64 - eqs) : 0;
        nc += poplt + kept_eq;
        eqs += popeq;
    }
    cnt = nc;
}

// Ballot-compact push of one 64-wide batch into the pool, with overflow pruning.
__device__ __forceinline__ void pool_push(float* kp, u32* ip, int& cnt, float& Tk,
                                          int lane, u64 lt, float key, u32 oidx, bool acc) {
    const u64 mask = __ballot(acc);
    if (mask) {
        if (acc) {
            const int s = cnt + (int)__popcll(mask & lt);
            kp[s] = key; ip[s] = oidx;
        }
        cnt += (int)__popcll(mask);
        if (cnt > CAP - 64) {
            pool_prune(kp, ip, cnt, Tk, lane, lt);
            if (cnt > CAP - 64) pool_hard_prune(kp, ip, cnt, lane, lt);
        }
    }
}

// ---------- grid build ----------
__global__ __launch_bounds__(256) void init_grid(u32* __restrict__ hist, u32* __restrict__ bbox) {
    const int i = blockIdx.x * 256 + threadIdx.x;
    if (i < G3) hist[i] = 0;
    if (i < 3) bbox[i] = 0xFFFFFFFFu;          // encoded mins
    else if (i < 6) bbox[i] = 0u;              // encoded maxs
}

__global__ __launch_bounds__(256) void bbox_kernel(const float* __restrict__ data,
                                                   u32* __restrict__ bbox) {
    const int i = blockIdx.x * 256 + threadIdx.x;
    const int lane = threadIdx.x & 63;
    float x = data[3*i], y = data[3*i+1], z = data[3*i+2];
    float mnx = x, mny = y, mnz = z, mxx = x, mxy = y, mxz = z;
    #pragma unroll
    for (int s = 1; s < 64; s <<= 1) {
        mnx = fminf(mnx, __shfl_xor(mnx, s, 64)); mxx = fmaxf(mxx, __shfl_xor(mxx, s, 64));
        mny = fminf(mny, __shfl_xor(mny, s, 64)); mxy = fmaxf(mxy, __shfl_xor(mxy, s, 64));
        mnz = fminf(mnz, __shfl_xor(mnz, s, 64)); mxz = fmaxf(mxz, __shfl_xor(mxz, s, 64));
    }
    if (lane == 0) {
        atomicMin(&bbox[0], fenc(mnx)); atomicMin(&bbox[1], fenc(mny)); atomicMin(&bbox[2], fenc(mnz));
        atomicMax(&bbox[3], fenc(mxx)); atomicMax(&bbox[4], fenc(mxy)); atomicMax(&bbox[5], fenc(mxz));
    }
}

__device__ __forceinline__ void grid_geom(const u32* bbox, float& mnx, float& mny, float& mnz,
                                          float& hx, float& hy, float& hz) {
    mnx = fdec(bbox[0]); mny = fdec(bbox[1]); mnz = fdec(bbox[2]);
    hx = fmaxf((fdec(bbox[3]) - mnx) * (1.0f / G), 1e-20f);
    hy = fmaxf((fdec(bbox[4]) - mny) * (1.0f / G), 1e-20f);
    hz = fmaxf((fdec(bbox[5]) - mnz) * (1.0f / G), 1e-20f);
}

__global__ __launch_bounds__(256) void cellid_hist(const float* __restrict__ data,
                                                   const u32* __restrict__ bbox,
                                                   u32* __restrict__ cellid,
                                                   u32* __restrict__ hist) {
    const int i = blockIdx.x * 256 + threadIdx.x;
    float mnx, mny, mnz, hx, hy, hz;
    grid_geom(bbox, mnx, mny, mnz, hx, hy, hz);
    const float x = data[3*i], y = data[3*i+1], z = data[3*i+2];
    const int cx = iclamp((int)((x - mnx) / hx), 0, G-1);
    const int cy = iclamp((int)((y - mny) / hy), 0, G-1);
    const int cz = iclamp((int)((z - mnz) / hz), 0, G-1);
    const u32 cid = (u32)((cz * G + cy) * G + cx);
    cellid[i] = cid;
    atomicAdd(&hist[cid], 1u);
}

#define SCAN_ITEMS 46   // 1024*46 = 47104 >= G3
__global__ __launch_bounds__(1024) void scan_cells(const u32* __restrict__ hist,
                                                   u32* __restrict__ cstart,
                                                   u32* __restrict__ cursor) {
    __shared__ u32 lds[1024];
    const int t = threadIdx.x;
    u32 v[SCAN_ITEMS]; u32 s = 0;
    #pragma unroll
    for (int j = 0; j < SCAN_ITEMS; ++j) {
        const int i = t * SCAN_ITEMS + j;
        const u32 h = (i < G3) ? hist[i] : 0u;
        v[j] = h; s += h;
    }
    lds[t] = s;
    __syncthreads();
    for (int off = 1; off < 1024; off *= 2) {
        const u32 add = (t >= off) ? lds[t - off] : 0u;
        __syncthreads();
        lds[t] += add;
        __syncthreads();
    }
    u32 run = lds[t] - s;   // exclusive prefix of this thread's chunk
    #pragma unroll
    for (int j = 0; j < SCAN_ITEMS; ++j) {
        const int i = t * SCAN_ITEMS + j;
        if (i < G3) { cstart[i] = run; cursor[i] = run; }
        run += v[j];
    }
    if (t == 1023) cstart[G3] = lds[1023];
}

__global__ __launch_bounds__(256) void scatter(const float* __restrict__ data,
                                               const u32* __restrict__ cellid,
                                               u32* __restrict__ cursor,
                                               float4* __restrict__ pts,
                                               u32* __restrict__ idxs) {
    const int i = blockIdx.x * 256 + threadIdx.x;
    const float x = data[3*i], y = data[3*i+1], z = data[3*i+2];
    const float d2 = __fadd_rn(__fadd_rn(__fmul_rn(x,x), __fmul_rn(y,y)), __fmul_rn(z,z));
    const u32 pos = atomicAdd(&cursor[cellid[i]], 1u);
    pts[pos] = make_float4(x, y, z, d2);
    idxs[pos] = (u32)i;
}

// ---------- main query kernel: one wave per query ----------
__global__ __launch_bounds__(256) void knn_grid(const float4* __restrict__ pts,
                                                const u32* __restrict__ idxs,
                                                const u32* __restrict__ cstart,
                                                const float* __restrict__ queries,
                                                const u32* __restrict__ bbox,
                                                int* __restrict__ out_nb,
                                                int* __restrict__ splits) {
    __shared__ float keyP[NWQ][CAP];
    __shared__ u32   idxP[NWQ][CAP];
    __shared__ int   accI[NWQ][KNB];

    const int lane = threadIdx.x & 63;
    const int wid  = threadIdx.x >> 6;
    const int q = blockIdx.x * NWQ + wid;
    const u64 lt = (1ull << lane) - 1ull;
    float* kp = keyP[wid];
    u32*   ip = idxP[wid];

    const float qx = queries[3*q], qy = queries[3*q+1], qz = queries[3*q+2];
    const float q2 = __fadd_rn(__fadd_rn(__fmul_rn(qx,qx), __fmul_rn(qy,qy)), __fmul_rn(qz,qz));

    float mnx, mny, mnz, hx, hy, hz;
    grid_geom(bbox, mnx, mny, mnz, hx, hy, hz);
    const float hmin = fminf(hx, fminf(hy, hz));
    const int cx = iclamp((int)((qx - mnx) / hx), 0, G-1);
    const int cy = iclamp((int)((qy - mny) / hy), 0, G-1);
    const int cz = iclamp((int)((qz - mnz) / hz), 0, G-1);

    // Phase A: smallest cube half-width W (cells) with >= KK points
    int W = 0, ccount = 0;
    while (ccount < KK && W < G) {
        ++W;
        const int side = 2*W + 1, nrows = side * side;
        ccount = 0;
        for (int r0 = 0; r0 < nrows; r0 += 64) {
            const int rid = r0 + lane;
            int s = 0, e = 0;
            if (rid < nrows) {
                const int dz = rid / side - W, dy = rid % side - W;
                const int zz = cz + dz, yy = cy + dy;
                if (zz >= 0 && zz < G && yy >= 0 && yy < G) {
                    const int xlo = cx - W < 0 ? 0 : cx - W;
                    const int xhi = cx + W > G-1 ? G-1 : cx + W;
                    const int rb = (zz * G + yy) * G;
                    s = (int)cstart[rb + xlo];
                    e = (int)cstart[rb + xhi + 1];
                }
            }
            ccount += wave_sum_i(e - s);
        }
    }

    float Tk = FINF; int cnt = 0;

    // Phase B1: gather cube-W through the pool -> exact k33 upper bound
    {
        const int side = 2*W + 1, nrows = side * side;
        for (int r0 = 0; r0 < nrows; r0 += 64) {
            const int rid = r0 + lane;
            int s = 0, e = 0;
            if (rid < nrows) {
                const int dz = rid / side - W, dy = rid % side - W;
                const int zz = cz + dz, yy = cy + dy;
                if (zz >= 0 && zz < G && yy >= 0 && yy < G) {
                    const int xlo = cx - W < 0 ? 0 : cx - W;
                    const int xhi = cx + W > G-1 ? G-1 : cx + W;
                    const int rb = (zz * G + yy) * G;
                    s = (int)cstart[rb + xlo];
                    e = (int)cstart[rb + xhi + 1];
                }
            }
            u64 live = __ballot(e > s);
            while (live) {
                const int rl = (int)__ffsll((unsigned long long)live) - 1;
                live &= live - 1;
                const int s_ = __shfl(s, rl, 64);
                const int e_ = __shfl(e, rl, 64);
                for (int p0 = s_; p0 < e_; p0 += 64) {
                    const int pi = p0 + lane;
                    const bool val = pi < e_;
                    float key = FINF; u32 oi = 0; bool acc = false;
                    if (val) {
                        const float4 w = pts[pi];
                        oi = idxs[pi];
                        const float dot = __fmaf_rn(qz, w.z, __fmaf_rn(qy, w.y, __fmul_rn(qx, w.x)));
                        const float sq  = __fsub_rn(__fadd_rn(q2, w.w), __fadd_rn(dot, dot));
                        key = fmaxf(sq, 0.0f);
                        acc = key <= Tk;
                    }
                    pool_push(kp, ip, cnt, Tk, lane, lt, key, oi, acc);
                }
            }
        }
    }

    float r[12];
    #pragma unroll
    for (int j = 0; j < 12; ++j) {
        const int s = j * 64 + lane;
        r[j] = (s < cnt) ? kp[s] : FINF;
    }
    const float k33b = bisect_rank(r, KK);                 // exact 33rd of cube multiset
    const float R2m = __fmaf_rn(k33b, 1.0002f, 1e-3f);     // margin: fp-fuzz of key & cell bounds

    // Phase B2: if ball(R2m) escapes cube-W (outside cells are >= W*hmin away), regather ball
    if (!(R2m < (float)W * (float)W * hmin * hmin)) {
        cnt = 0; Tk = k33b;
        const float Rm = sqrtf(R2m);
        const int Dz = (int)fminf(floorf(Rm / hz) + 1.0f, (float)G);
        const int Dy = (int)fminf(floorf(Rm / hy) + 1.0f, (float)G);
        const int sidey = 2*Dy + 1;
        const int nrows = (2*Dz + 1) * sidey;
        for (int r0 = 0; r0 < nrows; r0 += 64) {
            const int rid = r0 + lane;
            int s = 0, e = 0;
            if (rid < nrows) {
                const int dz = rid / sidey - Dz;
                const int dy = rid % sidey - Dy;
                const int zz = cz + dz, yy = cy + dy;
                if (zz >= 0 && zz < G && yy >= 0 && yy < G) {
                    const int adz = dz < 0 ? -dz : dz;
                    const int ady = dy < 0 ? -dy : dy;
                    const float mz = (adz >= 1) ? (float)(adz - 1) * hz : 0.0f;
                    const float my = (ady >= 1) ? (float)(ady - 1) * hy : 0.0f;
                    const float rowmin2 = mz*mz + my*my;
                    if (rowmin2 <= R2m) {
                        const int dxr = (int)fminf(floorf(sqrtf(R2m - rowmin2) / hx) + 1.0f, (float)G);
                        const int xlo = cx - dxr < 0 ? 0 : cx - dxr;
                        const int xhi = cx + dxr > G-1 ? G-1 : cx + dxr;
                        if (xlo <= xhi) {
                            const int rb = (zz * G + yy) * G;
                            s = (int)cstart[rb + xlo];
                            e = (int)cstart[rb + xhi + 1];
                        }
                    }
                }
            }
            u64 live = __ballot(e > s);
            while (live) {
                const int rl = (int)__ffsll((unsigned long long)live) - 1;
                live &= live - 1;
                const int s_ = __shfl(s, rl, 64);
                const int e_ = __shfl(e, rl, 64);
                for (int p0 = s_; p0 < e_; p0 += 64) {
                    const int pi = p0 + lane;
                    const bool val = pi < e_;
                    float key = FINF; u32 oi = 0; bool acc = false;
                    if (val) {
                        const float4 w = pts[pi];
                        oi = idxs[pi];
                        const float dot = __fmaf_rn(qz, w.z, __fmaf_rn(qy, w.y, __fmul_rn(qx, w.x)));
                        const float sq  = __fsub_rn(__fadd_rn(q2, w.w), __fadd_rn(dot, dot));
                        key = fmaxf(sq, 0.0f);
                        acc = key <= Tk;
                    }
                    pool_push(kp, ip, cnt, Tk, lane, lt, key, oi, acc);
                }
            }
        }
    }

    // exact global 33rd key: bitonic (cnt<=64 fast path) or bisect
    float k33;
    if (cnt <= 64) {
        float v = (lane < cnt) ? kp[lane] : FINF;
        #pragma unroll
        for (int k = 2; k <= 64; k <<= 1) {
            #pragma unroll
            for (int j = k >> 1; j >= 1; j >>= 1) {
                const float o = __shfl_xor(v, j, 64);
                const bool up = ((lane & k) == 0);
                const bool keepmin = (((lane & j) == 0) == up);
                v = keepmin ? fminf(v, o) : fmaxf(v, o);
            }
        }
        k33 = __shfl(v, KK - 1, 64);
    } else {
        #pragma unroll
        for (int j = 0; j < 12; ++j) {
            const int s = j * 64 + lane;
            r[j] = (s < cnt) ? kp[s] : FINF;
        }
        k33 = bisect_rank(r, KK);
    }

    // sqrt-domain cut (R4-proven): key < cut <=> sqrtf(key) < sqrtf(k33)
    const float kd = sqrtf(k33);
    float cut;
    if (!(kd > 0.0f)) {
        cut = -1.0f;
    } else {
        int bi = __float_as_int(__fmul_rn(kd, kd));
        #pragma unroll 1
        for (int s = 0; s < 8; ++s) {
            if (bi > 0 && sqrtf(__int_as_float(bi - 1)) >= kd) --bi; else break;
        }
        #pragma unroll 1
        for (int s = 0; s < 8; ++s) {
            if (sqrtf(__int_as_float(bi)) < kd) ++bi; else break;
        }
        cut = __int_as_float(bi);
    }

    // filter pool by key < cut, compact to accI (R4-proven)
    int c = 0;
    #pragma unroll 1
    for (int j0 = 0; j0 < cnt; j0 += 64) {
        const int j = j0 + lane;
        const bool val = j < cnt;
        const float k = val ? kp[j] : FINF;
        const bool keep = val && (k < cut);
        const u64 mask = __ballot(keep);
        if (keep) {
            const int s = c + (int)__popcll(mask & lt);
            if (s < KNB) accI[wid][s] = (int)ip[j];
        }
        c += (int)__popcll(mask);
    }
    if (c > KNB) c = KNB;

    // ranking sort by index ascending + padded row write (R4-proven)
    if (lane < KNB) {
        if (lane < c) {
            const int my = accI[wid][lane];
            int rank = 0;
            #pragma unroll 1
            for (int j = 0; j < KNB; ++j)
                if (j < c) rank += (accI[wid][j] < my) ? 1 : 0;
            out_nb[(size_t)q * KNB + rank] = my;
        } else {
            out_nb[(size_t)q * KNB + lane] = ND;
        }
    }
    if (lane == 0) splits[1 + q] = c;
}

// --- fallback (ws too small): direct per-thread scan (correct, slow) ---
__global__ __launch_bounds__(256) void knn_direct_kernel(const float* __restrict__ data,
                                                         const float* __restrict__ queries,
                                                         int* __restrict__ out_nb,
                                                         int* __restrict__ splits) {
    __shared__ float4 tile[1024];
    const int q = blockIdx.x * 256 + threadIdx.x;
    const float qx = queries[3*q], qy = queries[3*q+1], qz = queries[3*q+2];
    const float q2 = __fadd_rn(__fadd_rn(__fmul_rn(qx,qx), __fmul_rn(qy,qy)), __fmul_rn(qz,qz));
    float arrk[KK]; int arri[KK];
    for (int j = 0; j < KK; ++j) { arrk[j] = FINF; arri[j] = ND; }
    float cur_maxk = FINF;
    for (int t0 = 0; t0 < ND; t0 += 1024) {
        for (int p = threadIdx.x; p < 1024; p += 256) {
            const int g = t0 + p;
            const float x = data[3*g], y = data[3*g+1], z = data[3*g+2];
            const float d2 = __fadd_rn(__fadd_rn(__fmul_rn(x,x), __fmul_rn(y,y)), __fmul_rn(z,z));
            tile[p] = make_float4(x, y, z, d2);
        }
        __syncthreads();
        for (int p = 0; p < 1024; ++p) {
            const float4 dp = tile[p];
            const float dot = __fmaf_rn(qz, dp.z, __fmaf_rn(qy, dp.y, __fmul_rn(qx, dp.x)));
            const float sq  = __fsub_rn(__fadd_rn(q2, dp.w), __fadd_rn(dot, dot));
            const float key = fmaxf(sq, 0.0f);
            if (key < cur_maxk) {
                int mp = 0; float m = -1.0f;
                for (int j = 0; j < KK; ++j) if (arrk[j] > m) { m = arrk[j]; mp = j; }
                arrk[mp] = key; arri[mp] = t0 + p;
                m = -1.0f;
                for (int j = 0; j < KK; ++j) if (arrk[j] > m) m = arrk[j];
                cur_maxk = m;
            }
        }
        __syncthreads();
    }
    const float kdist = sqrtf(cur_maxk);
    int acc[KNB]; int c = 0;
    for (int j = 0; j < KK; ++j) {
        const float d = sqrtf(arrk[j]);
        if (d < kdist && c < KNB) acc[c++] = arri[j];
    }
    for (int a = 1; a < c; ++a) {
        const int v = acc[a]; int j = a;
        while (j > 0 && acc[j-1] > v) { acc[j] = acc[j-1]; --j; }
        acc[j] = v;
    }
    int* row = out_nb + (size_t)q * KNB;
    for (int j = 0; j < KNB; ++j) row[j] = (j < c) ? acc[j] : ND;
    splits[1 + q] = c;
}

// --- splits: in-place scan of counts (single block) ---
__global__ __launch_bounds__(1024) void splits_scan_kernel(int* __restrict__ splits) {
    __shared__ int lds[1024];
    const int t = threadIdx.x;
    int v[16]; int s = 0;
    #pragma unroll
    for (int j = 0; j < 16; ++j) { v[j] = splits[1 + t*16 + j]; s += v[j]; }
    lds[t] = s;
    __syncthreads();
    for (int off = 1; off < 1024; off *= 2) {
        const int add = (t >= off) ? lds[t - off] : 0;
        __syncthreads();
        lds[t] += add;
        __syncthreads();
    }
    int run = lds[t] - s;
    #pragma unroll
    for (int j = 0; j < 16; ++j) { run += v[j]; splits[1 + t*16 + j] = run; }
    if (t == 0) splits[0] = 0;
}

extern "C" void kernel_launch(void* const* d_in, const int* in_sizes, int n_in,
                              void* d_out, int out_size, void* d_ws, size_t ws_size,
                              hipStream_t stream) {
    const float* data    = (const float*)d_in[0];
    const float* queries = (const float*)d_in[1];
    int* out    = (int*)d_out;
    int* splits = out + SPLITS_BASE;

    // ws layout
    const size_t bbox_off   = 0;                                  // 6 u32 (pad 64)
    const size_t hist_off   = 64;
    const size_t cstart_off = hist_off + (size_t)G3 * 4;
    const size_t cursor_off = cstart_off + (size_t)(G3 + 1) * 4;
    const size_t cellid_off = cursor_off + (size_t)G3 * 4;
    size_t pts_off          = cellid_off + (size_t)ND * 4;
    pts_off = (pts_off + 255) & ~(size_t)255;
    const size_t idxs_off   = pts_off + (size_t)ND * 16;
    const size_t need       = idxs_off + (size_t)ND * 4;          // ~950 KB

    if (ws_size >= need) {
        u32*    bbox   = (u32*)((char*)d_ws + bbox_off);
        u32*    hist   = (u32*)((char*)d_ws + hist_off);
        u32*    cstart = (u32*)((char*)d_ws + cstart_off);
        u32*    cursor = (u32*)((char*)d_ws + cursor_off);
        u32*    cellid = (u32*)((char*)d_ws + cellid_off);
        float4* pts    = (float4*)((char*)d_ws + pts_off);
        u32*    idxs   = (u32*)((char*)d_ws + idxs_off);

        hipLaunchKernelGGL(init_grid, dim3((G3 + 255) / 256), dim3(256), 0, stream, hist, bbox);
        hipLaunchKernelGGL(bbox_kernel, dim3(ND / 256), dim3(256), 0, stream, data, bbox);
        hipLaunchKernelGGL(cellid_hist, dim3(ND / 256), dim3(256), 0, stream,
                           data, bbox, cellid, hist);
        hipLaunchKernelGGL(scan_cells, dim3(1), dim3(1024), 0, stream, hist, cstart, cursor);
        hipLaunchKernelGGL(scatter, dim3(ND / 256), dim3(256), 0, stream,
                           data, cellid, cursor, pts, idxs);
        hipLaunchKernelGGL(knn_grid, dim3(NQ / NWQ), dim3(256), 0, stream,
                           pts, idxs, cstart, queries, bbox, out, splits);
    } else {
        hipLaunchKernelGGL(knn_direct_kernel, dim3(NQ / 256), dim3(256), 0, stream,
                           data, queries, out, splits);
    }
    hipLaunchKernelGGL(splits_scan_kernel, dim3(1), dim3(1024), 0, stream, splits);
}

// Round 6
// 157.394 us; speedup vs baseline: 1.5827x; 1.5827x over previous
//
#include <hip/hip_runtime.h>
#include <stdint.h>

typedef unsigned long long u64;
typedef unsigned int u32;

#define NQ 16384
#define ND 16384
#define KNB 32                  // neighbors emitted per query
#define KK 33                   // need the 33rd-smallest (rank index 32)
#define SPLITS_BASE (NQ * KNB)  // 524288
#define CAP 512                 // LDS candidate pool per query
#define NRR (CAP / 64)          // 8 strided regs per lane
#define NWQ 4                   // queries (waves) per block
#define G 36
#define G3 (G*G*G)              // 46656 cells
#define FINF (__int_as_float(0x7f800000))

// Exact replication of reference arithmetic (same as passing R1-R5 kernels):
//   q2 = (qx*qx + qy*qy) + qz*qz ; d2 likewise (recomputed exactly per candidate)
//   dot = fma(qz,z, fma(qy,y, qx*x)) ; sq = (q2+d2) - (dot+dot)
//   key = fmaxf(sq,0) ; k = sqrtf(33rd smallest key) ; accept via ulp cut probe

// ---- wave helpers ----
// sum of small non-negative per-lane ints via independent ballots (no shfl chain)
template<int BITS>
__device__ __forceinline__ int wave_sum_small(int v) {
    int tot = 0;
    #pragma unroll
    for (int b = 0; b < BITS; ++b)
        tot += (int)__popcll(__ballot((v >> b) & 1)) << b;
    return tot;
}
__device__ __forceinline__ float wave_max_f(float v) {
    #pragma unroll
    for (int s = 1; s < 64; s <<= 1) v = fmaxf(v, __shfl_xor(v, s, 64));
    return v;
}
__device__ __forceinline__ int wave_excl_prefix(int v, int lane) {
    int x = v;
    #pragma unroll
    for (int s = 1; s < 64; s <<= 1) {
        const int y = __shfl_up(x, s, 64);
        if (lane >= s) x += y;
    }
    return x - v;
}
__device__ __forceinline__ int iclamp(int v, int lo, int hi) {
    return v < lo ? lo : (v > hi ? hi : v);
}

// min float f with #{r <= f} >= rank over the wave's strided regs (pads FINF).
// R4-proven logic; wave count now via ballots (c <= NRR=8 -> 4 bits).
__device__ __forceinline__ float bisect_rank8(const float (&r)[NRR], int rank) {
    u32 lo = 0u, hi = 0x7f800000u;
    #pragma unroll 1
    while (lo < hi) {
        const u32 mid = (lo + hi) >> 1;
        const float pv = __uint_as_float(mid);
        int c = 0;
        #pragma unroll
        for (int j = 0; j < NRR; ++j) c += (r[j] <= pv) ? 1 : 0;
        const int tot = wave_sum_small<4>(c);
        if (tot >= rank) hi = mid; else lo = mid + 1;
    }
    return __uint_as_float(hi);
}

// Cheap prune (R4-proven): keep key <= M where M = wave_max(lane minima) >= pool 33rd.
__device__ __forceinline__ void pool_prune(float* kp, u32* ip, int& cnt, float& Tk,
                                           int lane, u64 lt) {
    float m = FINF;
    #pragma unroll 1
    for (int j = lane; j < cnt; j += 64) m = fminf(m, kp[j]);
    const float M = wave_max_f(m);
    int nc = 0;
    #pragma unroll 1
    for (int j0 = 0; j0 < cnt; j0 += 64) {
        const int j = j0 + lane;
        const bool val = j < cnt;
        float k = FINF; u32 id = 0;
        if (val) { k = kp[j]; id = ip[j]; }
        const bool keep = val && (k <= M);
        const u64 mask = __ballot(keep);
        if (keep) {
            const int s = nc + (int)__popcll(mask & lt);
            kp[s] = k; ip[s] = id;
        }
        nc += (int)__popcll(mask);
    }
    cnt = nc; Tk = M;
}

// Degenerate-tie path (R4-proven): keep key < v (v = exact 64th) plus <= 64 copies == v.
__device__ __forceinline__ void pool_hard_prune(float* kp, u32* ip, int& cnt,
                                                int lane, u64 lt) {
    float r[NRR];
    #pragma unroll
    for (int j = 0; j < NRR; ++j) {
        const int s = j * 64 + lane;
        r[j] = (s < cnt) ? kp[s] : FINF;
    }
    const float v = bisect_rank8(r, 64);
    int nc = 0, eqs = 0;
    #pragma unroll 1
    for (int j0 = 0; j0 < cnt; j0 += 64) {
        const int j = j0 + lane;
        const bool val = j < cnt;
        float k = FINF; u32 id = 0;
        if (val) { k = kp[j]; id = ip[j]; }
        const bool lt_v = val && (k < v);
        const bool eq_v = val && (k == v);
        const u64 mlt = __ballot(lt_v);
        const u64 meq = __ballot(eq_v);
        const int poplt = (int)__popcll(mlt);
        const int popeq = (int)__popcll(meq);
        if (lt_v) { const int s = nc + (int)__popcll(mlt & lt); kp[s] = k; ip[s] = id; }
        if (eq_v) {
            const int pe = (int)__popcll(meq & lt);
            if (eqs + pe < 64) { const int s = nc + poplt + pe; kp[s] = k; ip[s] = id; }
        }
        int kept_eq = popeq;
        if (eqs + popeq > 64) kept_eq = (64 - eqs > 0) ? (64 - eqs) : 0;
        nc += poplt + kept_eq;
        eqs += popeq;
    }
    cnt = nc;
}

// ---------- grid build ----------
// prep: zero hist + bbox reduce (single block, no atomics needed)
__global__ __launch_bounds__(1024) void prep(const float* __restrict__ data,
                                             u32* __restrict__ hist,
                                             float* __restrict__ bb) {
    __shared__ float red[6][16];
    for (int i = threadIdx.x; i < G3; i += 1024) hist[i] = 0u;
    float mnx = FINF, mny = FINF, mnz = FINF, mxx = -FINF, mxy = -FINF, mxz = -FINF;
    for (int i = threadIdx.x; i < ND; i += 1024) {
        const float x = data[3*i], y = data[3*i+1], z = data[3*i+2];
        mnx = fminf(mnx, x); mxx = fmaxf(mxx, x);
        mny = fminf(mny, y); mxy = fmaxf(mxy, y);
        mnz = fminf(mnz, z); mxz = fmaxf(mxz, z);
    }
    #pragma unroll
    for (int s = 1; s < 64; s <<= 1) {
        mnx = fminf(mnx, __shfl_xor(mnx, s, 64)); mxx = fmaxf(mxx, __shfl_xor(mxx, s, 64));
        mny = fminf(mny, __shfl_xor(mny, s, 64)); mxy = fmaxf(mxy, __shfl_xor(mxy, s, 64));
        mnz = fminf(mnz, __shfl_xor(mnz, s, 64)); mxz = fmaxf(mxz, __shfl_xor(mxz, s, 64));
    }
    const int wv = threadIdx.x >> 6;
    if ((threadIdx.x & 63) == 0) {
        red[0][wv] = mnx; red[1][wv] = mny; red[2][wv] = mnz;
        red[3][wv] = mxx; red[4][wv] = mxy; red[5][wv] = mxz;
    }
    __syncthreads();
    if (threadIdx.x == 0) {
        float a0 = red[0][0], a1 = red[1][0], a2 = red[2][0];
        float a3 = red[3][0], a4 = red[4][0], a5 = red[5][0];
        for (int w = 1; w < 16; ++w) {
            a0 = fminf(a0, red[0][w]); a1 = fminf(a1, red[1][w]); a2 = fminf(a2, red[2][w]);
            a3 = fmaxf(a3, red[3][w]); a4 = fmaxf(a4, red[4][w]); a5 = fmaxf(a5, red[5][w]);
        }
        bb[0] = a0; bb[1] = a1; bb[2] = a2; bb[3] = a3; bb[4] = a4; bb[5] = a5;
    }
}

__device__ __forceinline__ void grid_geom(const float* bb, float& mnx, float& mny, float& mnz,
                                          float& hx, float& hy, float& hz) {
    mnx = bb[0]; mny = bb[1]; mnz = bb[2];
    hx = fmaxf((bb[3] - mnx) * (1.0f / G), 1e-20f);
    hy = fmaxf((bb[4] - mny) * (1.0f / G), 1e-20f);
    hz = fmaxf((bb[5] - mnz) * (1.0f / G), 1e-20f);
}

__device__ __forceinline__ u32 cell_of(const float* bb, float x, float y, float z) {
    float mnx, mny, mnz, hx, hy, hz;
    grid_geom(bb, mnx, mny, mnz, hx, hy, hz);
    const int cx = iclamp((int)((x - mnx) / hx), 0, G-1);
    const int cy = iclamp((int)((y - mny) / hy), 0, G-1);
    const int cz = iclamp((int)((z - mnz) / hz), 0, G-1);
    return (u32)((cz * G + cy) * G + cx);
}

__global__ __launch_bounds__(256) void cellid_hist(const float* __restrict__ data,
                                                   const float* __restrict__ bb,
                                                   u32* __restrict__ hist) {
    const int i = blockIdx.x * 256 + threadIdx.x;
    atomicAdd(&hist[cell_of(bb, data[3*i], data[3*i+1], data[3*i+2])], 1u);
}

#define SCAN_ITEMS 46   // 1024*46 = 47104 >= G3
__global__ __launch_bounds__(1024) void scan_cells(const u32* __restrict__ hist,
                                                   u32* __restrict__ cstart,
                                                   u32* __restrict__ cursor) {
    __shared__ u32 lds[1024];
    const int t = threadIdx.x;
    u32 v[SCAN_ITEMS]; u32 s = 0;
    #pragma unroll
    for (int j = 0; j < SCAN_ITEMS; ++j) {
        const int i = t * SCAN_ITEMS + j;
        const u32 h = (i < G3) ? hist[i] : 0u;
        v[j] = h; s += h;
    }
    lds[t] = s;
    __syncthreads();
    for (int off = 1; off < 1024; off *= 2) {
        const u32 add = (t >= off) ? lds[t - off] : 0u;
        __syncthreads();
        lds[t] += add;
        __syncthreads();
    }
    u32 run = lds[t] - s;
    #pragma unroll
    for (int j = 0; j < SCAN_ITEMS; ++j) {
        const int i = t * SCAN_ITEMS + j;
        if (i < G3) { cstart[i] = run; cursor[i] = run; }
        run += v[j];
    }
    if (t == 1023) cstart[G3] = lds[1023];
}

// pts = (x, y, z, bitcast(original idx)) — one 16B load per candidate
__global__ __launch_bounds__(256) void scatter(const float* __restrict__ data,
                                               const float* __restrict__ bb,
                                               u32* __restrict__ cursor,
                                               float4* __restrict__ pts) {
    const int i = blockIdx.x * 256 + threadIdx.x;
    const float x = data[3*i], y = data[3*i+1], z = data[3*i+2];
    const u32 pos = atomicAdd(&cursor[cell_of(bb, x, y, z)], 1u);
    pts[pos] = make_float4(x, y, z, __uint_as_float((u32)i));
}

// ---------- main query kernel: one wave per query ----------
__global__ __launch_bounds__(256) void knn_grid(const float4* __restrict__ pts,
                                                const u32* __restrict__ cstart,
                                                const float* __restrict__ queries,
                                                const float* __restrict__ bb,
                                                int* __restrict__ out_nb,
                                                int* __restrict__ splits) {
    __shared__ float keyP[NWQ][CAP];
    __shared__ u32   idxP[NWQ][CAP];
    __shared__ int   accI[NWQ][KNB];

    const int lane = threadIdx.x & 63;
    const int wid  = threadIdx.x >> 6;
    const int q = blockIdx.x * NWQ + wid;
    const u64 lt = (1ull << lane) - 1ull;
    float* kp = keyP[wid];
    u32*   ip = idxP[wid];

    const float qx = queries[3*q], qy = queries[3*q+1], qz = queries[3*q+2];
    const float q2 = __fadd_rn(__fadd_rn(__fmul_rn(qx,qx), __fmul_rn(qy,qy)), __fmul_rn(qz,qz));

    float mnx, mny, mnz, hx, hy, hz;
    grid_geom(bb, mnx, mny, mnz, hx, hy, hz);
    const float hmin = fminf(hx, fminf(hy, hz));
    const int cx = iclamp((int)((qx - mnx) / hx), 0, G-1);
    const int cy = iclamp((int)((qy - mny) / hy), 0, G-1);
    const int cz = iclamp((int)((qz - mnz) / hz), 0, G-1);

    float Tk = FINF;   // running accept threshold (wave-uniform)
    int cnt = 0;       // pool count (wave-uniform)

    // dense gather of one 64-row batch: lanes hold 2 segments (sA,lA / sB,lB)
    auto gather_batch = [&](int sA, int lA, int sB, int lB) {
        const int len = lA + lB;
        const int P = wave_excl_prefix(len, lane);
        const int T = __shfl(P + len, 63, 64);
        #pragma unroll 1
        for (int g0 = 0; g0 < T; g0 += 64) {
            const int pos = g0 + lane;
            const bool val = pos < T;
            int rsel = 0;                       // max r with P[r] <= pos (skips len-0 rows)
            #pragma unroll
            for (int st = 32; st >= 1; st >>= 1) {
                const int t = rsel + st;
                const int Pt = __shfl(P, t, 64);
                if (Pt <= pos) rsel = t;
            }
            const int Pr  = __shfl(P,  rsel, 64);
            const int sAr = __shfl(sA, rsel, 64);
            const int lAr = __shfl(lA, rsel, 64);
            const int sBr = __shfl(sB, rsel, 64);
            const int off = pos - Pr;
            const int pi = (off < lAr) ? (sAr + off) : (sBr + (off - lAr));
            float key = FINF; u32 oi = 0; bool acc = false;
            if (val) {
                const float4 w = pts[pi];
                oi = __float_as_uint(w.w);
                const float d2 = __fadd_rn(__fadd_rn(__fmul_rn(w.x,w.x), __fmul_rn(w.y,w.y)),
                                           __fmul_rn(w.z,w.z));
                const float dot = __fmaf_rn(qz, w.z, __fmaf_rn(qy, w.y, __fmul_rn(qx, w.x)));
                const float sq  = __fsub_rn(__fadd_rn(q2, d2), __fadd_rn(dot, dot));
                key = fmaxf(sq, 0.0f);
                acc = key <= Tk;
            }
            const u64 mask = __ballot(acc);
            if (mask) {
                if (acc) {
                    const int s = cnt + (int)__popcll(mask & lt);
                    kp[s] = key; ip[s] = oi;
                }
                cnt += (int)__popcll(mask);
                if (cnt > CAP - 64) {
                    pool_prune(kp, ip, cnt, Tk, lane, lt);
                    if (cnt > CAP - 64) pool_hard_prune(kp, ip, cnt, lane, lt);
                }
            }
        }
    };

    // Phase A: smallest cube half-width W (cells) with >= KK points
    // (count saturated at 63/lane: sum >= KK detection is exact — see ballot-sum note)
    int W = 0;
    {
        int ccount = 0;
        while (ccount < KK && W < G) {
            ++W;
            const int side = 2*W + 1, nrows = side * side;
            ccount = 0;
            for (int r0 = 0; r0 < nrows; r0 += 64) {
                const int rid = r0 + lane;
                int len = 0;
                if (rid < nrows) {
                    const int dz = rid / side - W, dy = rid % side - W;
                    const int zz = cz + dz, yy = cy + dy;
                    if (zz >= 0 && zz < G && yy >= 0 && yy < G) {
                        const int xlo = cx - W < 0 ? 0 : cx - W;
                        const int xhi = cx + W > G-1 ? G-1 : cx + W;
                        const int rb = (zz * G + yy) * G;
                        len = (int)cstart[rb + xhi + 1] - (int)cstart[rb + xlo];
                    }
                }
                ccount += wave_sum_small<6>(len < 63 ? len : 63);
            }
        }
    }

    // Phase B1: dense gather of cube-W
    {
        const int side = 2*W + 1, nrows = side * side;
        for (int r0 = 0; r0 < nrows; r0 += 64) {
            const int rid = r0 + lane;
            int sA = 0, lA = 0;
            if (rid < nrows) {
                const int dz = rid / side - W, dy = rid % side - W;
                const int zz = cz + dz, yy = cy + dy;
                if (zz >= 0 && zz < G && yy >= 0 && yy < G) {
                    const int xlo = cx - W < 0 ? 0 : cx - W;
                    const int xhi = cx + W > G-1 ? G-1 : cx + W;
                    const int rb = (zz * G + yy) * G;
                    sA = (int)cstart[rb + xlo];
                    lA = (int)cstart[rb + xhi + 1] - sA;
                }
            }
            gather_batch(sA, lA, 0, 0);
        }
    }

    // exact 33rd of cube multiset (bitonic if small, else ballot-bisect)
    float k33b;
    if (cnt <= 64) {
        float v = (lane < cnt) ? kp[lane] : FINF;
        #pragma unroll
        for (int k = 2; k <= 64; k <<= 1) {
            #pragma unroll
            for (int j = k >> 1; j >= 1; j >>= 1) {
                const float o = __shfl_xor(v, j, 64);
                const bool up = ((lane & k) == 0);
                const bool keepmin = (((lane & j) == 0) == up);
                v = keepmin ? fminf(v, o) : fmaxf(v, o);
            }
        }
        k33b = __shfl(v, KK - 1, 64);
    } else {
        float r[NRR];
        #pragma unroll
        for (int j = 0; j < NRR; ++j) {
            const int s = j * 64 + lane;
            r[j] = (s < cnt) ? kp[s] : FINF;
        }
        k33b = bisect_rank8(r, KK);
    }

    // compact pool to keys <= k33b (preserves 33rd & all output candidates), Tk tight
    {
        int nc = 0;
        #pragma unroll 1
        for (int j0 = 0; j0 < cnt; j0 += 64) {
            const int j = j0 + lane;
            const bool val = j < cnt;
            float k = FINF; u32 id = 0;
            if (val) { k = kp[j]; id = ip[j]; }
            const bool keep = val && (k <= k33b);
            const u64 mask = __ballot(keep);
            if (keep) {
                const int s = nc + (int)__popcll(mask & lt);
                kp[s] = k; ip[s] = id;
            }
            nc += (int)__popcll(mask);
        }
        cnt = nc; Tk = k33b;
    }

    // Phase B2: ring gather (ball minus cube) if ball(R2m) escapes cube-W
    const float R2m = __fmaf_rn(k33b, 1.0002f, 1e-3f);   // R5-proven margin
    if (!(R2m < (float)W * (float)W * hmin * hmin)) {
        const float Rm = sqrtf(R2m);
        const int Dz = (int)fminf(floorf(Rm / hz) + 1.0f, (float)G);
        const int Dy = (int)fminf(floorf(Rm / hy) + 1.0f, (float)G);
        const int sidey = 2*Dy + 1;
        const int nrows = (2*Dz + 1) * sidey;
        for (int r0 = 0; r0 < nrows; r0 += 64) {
            const int rid = r0 + lane;
            int sA = 0, lA = 0, sB = 0, lB = 0;
            if (rid < nrows) {
                const int dz = rid / sidey - Dz;
                const int dy = rid % sidey - Dy;
                const int zz = cz + dz, yy = cy + dy;
                if (zz >= 0 && zz < G && yy >= 0 && yy < G) {
                    const int adz = dz < 0 ? -dz : dz;
                    const int ady = dy < 0 ? -dy : dy;
                    const float mz = (adz >= 1) ? (float)(adz - 1) * hz : 0.0f;
                    const float my = (ady >= 1) ? (float)(ady - 1) * hy : 0.0f;
                    const float rowmin2 = mz*mz + my*my;
                    if (rowmin2 <= R2m) {
                        const int dxr = (int)fminf(floorf(sqrtf(R2m - rowmin2) / hx) + 1.0f, (float)G);
                        const int xlo = cx - dxr < 0 ? 0 : cx - dxr;
                        const int xhi = cx + dxr > G-1 ? G-1 : cx + dxr;
                        if (xlo <= xhi) {
                            const int rb = (zz * G + yy) * G;
                            if (adz <= W && ady <= W) {
                                // subtract already-gathered cube x-range
                                const int xhiA = (cx - W - 1 < xhi) ? cx - W - 1 : xhi;
                                const int xloB = (cx + W + 1 > xlo) ? cx + W + 1 : xlo;
                                if (xlo <= xhiA) {
                                    sA = (int)cstart[rb + xlo];
                                    lA = (int)cstart[rb + xhiA + 1] - sA;
                                }
                                if (xloB <= xhi) {
                                    sB = (int)cstart[rb + xloB];
                                    lB = (int)cstart[rb + xhi + 1] - sB;
                                }
                            } else {
                                sA = (int)cstart[rb + xlo];
                                lA = (int)cstart[rb + xhi + 1] - sA;
                            }
                        }
                    }
                }
            }
            gather_batch(sA, lA, sB, lB);
        }
    }

    // exact global 33rd key (pool is small now: bitonic common path, bisect fallback)
    float k33;
    if (cnt <= 64) {
        float v = (lane < cnt) ? kp[lane] : FINF;
        #pragma unroll
        for (int k = 2; k <= 64; k <<= 1) {
            #pragma unroll
            for (int j = k >> 1; j >= 1; j >>= 1) {
                const float o = __shfl_xor(v, j, 64);
                const bool up = ((lane & k) == 0);
                const bool keepmin = (((lane & j) == 0) == up);
                v = keepmin ? fminf(v, o) : fmaxf(v, o);
            }
        }
        k33 = __shfl(v, KK - 1, 64);
    } else {
        float r[NRR];
        #pragma unroll
        for (int j = 0; j < NRR; ++j) {
            const int s = j * 64 + lane;
            r[j] = (s < cnt) ? kp[s] : FINF;
        }
        k33 = bisect_rank8(r, KK);
    }

    // sqrt-domain cut (R4-proven): key < cut <=> sqrtf(key) < sqrtf(k33)
    const float kd = sqrtf(k33);
    float cut;
    if (!(kd > 0.0f)) {
        cut = -1.0f;
    } else {
        int bi = __float_as_int(__fmul_rn(kd, kd));
        #pragma unroll 1
        for (int s = 0; s < 8; ++s) {
            if (bi > 0 && sqrtf(__int_as_float(bi - 1)) >= kd) --bi; else break;
        }
        #pragma unroll 1
        for (int s = 0; s < 8; ++s) {
            if (sqrtf(__int_as_float(bi)) < kd) ++bi; else break;
        }
        cut = __int_as_float(bi);
    }

    // filter pool by key < cut, compact to accI (R4-proven)
    int c = 0;
    #pragma unroll 1
    for (int j0 = 0; j0 < cnt; j0 += 64) {
        const int j = j0 + lane;
        const bool val = j < cnt;
        const float k = val ? kp[j] : FINF;
        const bool keep = val && (k < cut);
        const u64 mask = __ballot(keep);
        if (keep) {
            const int s = c + (int)__popcll(mask & lt);
            if (s < KNB) accI[wid][s] = (int)ip[j];
        }
        c += (int)__popcll(mask);
    }
    if (c > KNB) c = KNB;

    // ranking sort by index ascending + padded row write (R4-proven)
    if (lane < KNB) {
        if (lane < c) {
            const int my = accI[wid][lane];
            int rank = 0;
            #pragma unroll 1
            for (int j = 0; j < KNB; ++j)
                if (j < c) rank += (accI[wid][j] < my) ? 1 : 0;
            out_nb[(size_t)q * KNB + rank] = my;
        } else {
            out_nb[(size_t)q * KNB + lane] = ND;
        }
    }
    if (lane == 0) splits[1 + q] = c;
}

// --- fallback (ws too small): direct per-thread scan (correct, slow) ---
__global__ __launch_bounds__(256) void knn_direct_kernel(const float* __restrict__ data,
                                                         const float* __restrict__ queries,
                                                         int* __restrict__ out_nb,
                                                         int* __restrict__ splits) {
    __shared__ float4 tile[1024];
    const int q = blockIdx.x * 256 + threadIdx.x;
    const float qx = queries[3*q], qy = queries[3*q+1], qz = queries[3*q+2];
    const float q2 = __fadd_rn(__fadd_rn(__fmul_rn(qx,qx), __fmul_rn(qy,qy)), __fmul_rn(qz,qz));
    float arrk[KK]; int arri[KK];
    for (int j = 0; j < KK; ++j) { arrk[j] = FINF; arri[j] = ND; }
    float cur_maxk = FINF;
    for (int t0 = 0; t0 < ND; t0 += 1024) {
        for (int p = threadIdx.x; p < 1024; p += 256) {
            const int g = t0 + p;
            const float x = data[3*g], y = data[3*g+1], z = data[3*g+2];
            const float d2 = __fadd_rn(__fadd_rn(__fmul_rn(x,x), __fmul_rn(y,y)), __fmul_rn(z,z));
            tile[p] = make_float4(x, y, z, d2);
        }
        __syncthreads();
        for (int p = 0; p < 1024; ++p) {
            const float4 dp = tile[p];
            const float dot = __fmaf_rn(qz, dp.z, __fmaf_rn(qy, dp.y, __fmul_rn(qx, dp.x)));
            const float sq  = __fsub_rn(__fadd_rn(q2, dp.w), __fadd_rn(dot, dot));
            const float key = fmaxf(sq, 0.0f);
            if (key < cur_maxk) {
                int mp = 0; float m = -1.0f;
                for (int j = 0; j < KK; ++j) if (arrk[j] > m) { m = arrk[j]; mp = j; }
                arrk[mp] = key; arri[mp] = t0 + p;
                m = -1.0f;
                for (int j = 0; j < KK; ++j) if (arrk[j] > m) m = arrk[j];
                cur_maxk = m;
            }
        }
        __syncthreads();
    }
    const float kdist = sqrtf(cur_maxk);
    int acc[KNB]; int c = 0;
    for (int j = 0; j < KK; ++j) {
        const float d = sqrtf(arrk[j]);
        if (d < kdist && c < KNB) acc[c++] = arri[j];
    }
    for (int a = 1; a < c; ++a) {
        const int v = acc[a]; int j = a;
        while (j > 0 && acc[j-1] > v) { acc[j] = acc[j-1]; --j; }
        acc[j] = v;
    }
    int* row = out_nb + (size_t)q * KNB;
    for (int j = 0; j < KNB; ++j) row[j] = (j < c) ? acc[j] : ND;
    splits[1 + q] = c;
}

// --- splits: in-place scan of counts (single block) ---
__global__ __launch_bounds__(1024) void splits_scan_kernel(int* __restrict__ splits) {
    __shared__ int lds[1024];
    const int t = threadIdx.x;
    int v[16]; int s = 0;
    #pragma unroll
    for (int j = 0; j < 16; ++j) { v[j] = splits[1 + t*16 + j]; s += v[j]; }
    lds[t] = s;
    __syncthreads();
    for (int off = 1; off < 1024; off *= 2) {
        const int add = (t >= off) ? lds[t - off] : 0;
        __syncthreads();
        lds[t] += add;
        __syncthreads();
    }
    int run = lds[t] - s;
    #pragma unroll
    for (int j = 0; j < 16; ++j) { run += v[j]; splits[1 + t*16 + j] = run; }
    if (t == 0) splits[0] = 0;
}

extern "C" void kernel_launch(void* const* d_in, const int* in_sizes, int n_in,
                              void* d_out, int out_size, void* d_ws, size_t ws_size,
                              hipStream_t stream) {
    const float* data    = (const float*)d_in[0];
    const float* queries = (const float*)d_in[1];
    int* out    = (int*)d_out;
    int* splits = out + SPLITS_BASE;

    // ws layout
    const size_t bb_off     = 0;                                   // 6 floats (pad 64)
    const size_t hist_off   = 64;
    const size_t cstart_off = hist_off + (size_t)G3 * 4;
    const size_t cursor_off = cstart_off + (size_t)(G3 + 1) * 4;
    size_t pts_off          = cursor_off + (size_t)G3 * 4;
    pts_off = (pts_off + 255) & ~(size_t)255;
    const size_t need       = pts_off + (size_t)ND * 16;           // ~820 KB

    if (ws_size >= need) {
        float*  bb     = (float*)((char*)d_ws + bb_off);
        u32*    hist   = (u32*)((char*)d_ws + hist_off);
        u32*    cstart = (u32*)((char*)d_ws + cstart_off);
        u32*    cursor = (u32*)((char*)d_ws + cursor_off);
        float4* pts    = (float4*)((char*)d_ws + pts_off);

        hipLaunchKernelGGL(prep, dim3(1), dim3(1024), 0, stream, data, hist, bb);
        hipLaunchKernelGGL(cellid_hist, dim3(ND / 256), dim3(256), 0, stream, data, bb, hist);
        hipLaunchKernelGGL(scan_cells, dim3(1), dim3(1024), 0, stream, hist, cstart, cursor);
        hipLaunchKernelGGL(scatter, dim3(ND / 256), dim3(256), 0, stream, data, bb, cursor, pts);
        hipLaunchKernelGGL(knn_grid, dim3(NQ / NWQ), dim3(256), 0, stream,
                           pts, cstart, queries, bb, out, splits);
    } else {
        hipLaunchKernelGGL(knn_direct_kernel, dim3(NQ / 256), dim3(256), 0, stream,
                           data, queries, out, splits);
    }
    hipLaunchKernelGGL(splits_scan_kernel, dim3(1), dim3(1024), 0, stream, splits);
}

// Round 7
// 117.412 us; speedup vs baseline: 2.1216x; 1.3405x over previous
//
#include <hip/hip_runtime.h>
#include <stdint.h>

typedef unsigned long long u64;
typedef unsigned int u32;

#define NQ 16384
#define ND 16384
#define KNB 32                  // neighbors emitted per query
#define KK 33                   // need the 33rd-smallest (rank index 32)
#define SPLITS_BASE (NQ * KNB)  // 524288
#define CAP 512                 // LDS candidate pool per query
#define NRR (CAP / 64)          // 8 strided regs per lane
#define NWQ 4                   // queries (waves) per block
#define G 36
#define G3 (G*G*G)              // 46656 cells
#define SCB ((G3 + 255) / 256)  // 183 scan blocks
#define FINF (__int_as_float(0x7f800000))

// Exact replication of reference arithmetic (same as passing R1-R6 kernels):
//   q2 = (qx*qx + qy*qy) + qz*qz ; d2 likewise (recomputed exactly per candidate)
//   dot = fma(qz,z, fma(qy,y, qx*x)) ; sq = (q2+d2) - (dot+dot)
//   key = fmaxf(sq,0) ; k = sqrtf(33rd smallest key) ; accept via ulp cut probe

// ---- wave helpers ----
template<int BITS>
__device__ __forceinline__ int wave_sum_small(int v) {
    int tot = 0;
    #pragma unroll
    for (int b = 0; b < BITS; ++b)
        tot += (int)__popcll(__ballot((v >> b) & 1)) << b;
    return tot;
}
__device__ __forceinline__ float wave_max_f(float v) {
    #pragma unroll
    for (int s = 1; s < 64; s <<= 1) v = fmaxf(v, __shfl_xor(v, s, 64));
    return v;
}
__device__ __forceinline__ int wave_excl_prefix(int v, int lane) {
    int x = v;
    #pragma unroll
    for (int s = 1; s < 64; s <<= 1) {
        const int y = __shfl_up(x, s, 64);
        if (lane >= s) x += y;
    }
    return x - v;
}
__device__ __forceinline__ int iclamp(int v, int lo, int hi) {
    return v < lo ? lo : (v > hi ? hi : v);
}
__device__ __forceinline__ u32 fenc(float f) {
    const u32 u = __float_as_uint(f);
    return (u & 0x80000000u) ? ~u : (u | 0x80000000u);
}
__device__ __forceinline__ float fdec(u32 e) {
    const u32 u = (e & 0x80000000u) ? (e & 0x7fffffffu) : ~e;
    return __uint_as_float(u);
}

// min float f with #{r <= f} >= rank over the wave's strided regs (pads FINF). (R4-proven)
__device__ __forceinline__ float bisect_rank8(const float (&r)[NRR], int rank) {
    u32 lo = 0u, hi = 0x7f800000u;
    #pragma unroll 1
    while (lo < hi) {
        const u32 mid = (lo + hi) >> 1;
        const float pv = __uint_as_float(mid);
        int c = 0;
        #pragma unroll
        for (int j = 0; j < NRR; ++j) c += (r[j] <= pv) ? 1 : 0;
        const int tot = wave_sum_small<4>(c);
        if (tot >= rank) hi = mid; else lo = mid + 1;
    }
    return __uint_as_float(hi);
}

// Cheap prune (R4-proven): keep key <= M where M = wave_max(lane minima) >= pool 33rd.
__device__ __forceinline__ void pool_prune(float* kp, u32* ip, int& cnt, float& Tk,
                                           int lane, u64 lt) {
    float m = FINF;
    #pragma unroll 1
    for (int j = lane; j < cnt; j += 64) m = fminf(m, kp[j]);
    const float M = wave_max_f(m);
    int nc = 0;
    #pragma unroll 1
    for (int j0 = 0; j0 < cnt; j0 += 64) {
        const int j = j0 + lane;
        const bool val = j < cnt;
        float k = FINF; u32 id = 0;
        if (val) { k = kp[j]; id = ip[j]; }
        const bool keep = val && (k <= M);
        const u64 mask = __ballot(keep);
        if (keep) {
            const int s = nc + (int)__popcll(mask & lt);
            kp[s] = k; ip[s] = id;
        }
        nc += (int)__popcll(mask);
    }
    cnt = nc; Tk = M;
}

// Degenerate-tie path (R4-proven): keep key < v (v = exact 64th) plus <= 64 copies == v.
__device__ __forceinline__ void pool_hard_prune(float* kp, u32* ip, int& cnt,
                                                int lane, u64 lt) {
    float r[NRR];
    #pragma unroll
    for (int j = 0; j < NRR; ++j) {
        const int s = j * 64 + lane;
        r[j] = (s < cnt) ? kp[s] : FINF;
    }
    const float v = bisect_rank8(r, 64);
    int nc = 0, eqs = 0;
    #pragma unroll 1
    for (int j0 = 0; j0 < cnt; j0 += 64) {
        const int j = j0 + lane;
        const bool val = j < cnt;
        float k = FINF; u32 id = 0;
        if (val) { k = kp[j]; id = ip[j]; }
        const bool lt_v = val && (k < v);
        const bool eq_v = val && (k == v);
        const u64 mlt = __ballot(lt_v);
        const u64 meq = __ballot(eq_v);
        const int poplt = (int)__popcll(mlt);
        const int popeq = (int)__popcll(meq);
        if (lt_v) { const int s = nc + (int)__popcll(mlt & lt); kp[s] = k; ip[s] = id; }
        if (eq_v) {
            const int pe = (int)__popcll(meq & lt);
            if (eqs + pe < 64) { const int s = nc + poplt + pe; kp[s] = k; ip[s] = id; }
        }
        int kept_eq = popeq;
        if (eqs + popeq > 64) kept_eq = (64 - eqs > 0) ? (64 - eqs) : 0;
        nc += poplt + kept_eq;
        eqs += popeq;
    }
    cnt = nc;
}

// ---------- grid build ----------
// bbox: 64-block fenc-atomic reduction (bbox pre-initialized via memsetAsync)
__global__ __launch_bounds__(256) void bbox_kernel(const float* __restrict__ data,
                                                   u32* __restrict__ bbe) {
    const int i = blockIdx.x * 256 + threadIdx.x;
    const int lane = threadIdx.x & 63;
    float x = data[3*i], y = data[3*i+1], z = data[3*i+2];
    float mnx = x, mny = y, mnz = z, mxx = x, mxy = y, mxz = z;
    #pragma unroll
    for (int s = 1; s < 64; s <<= 1) {
        mnx = fminf(mnx, __shfl_xor(mnx, s, 64)); mxx = fmaxf(mxx, __shfl_xor(mxx, s, 64));
        mny = fminf(mny, __shfl_xor(mny, s, 64)); mxy = fmaxf(mxy, __shfl_xor(mxy, s, 64));
        mnz = fminf(mnz, __shfl_xor(mnz, s, 64)); mxz = fmaxf(mxz, __shfl_xor(mxz, s, 64));
    }
    if (lane == 0) {
        atomicMin(&bbe[0], fenc(mnx)); atomicMin(&bbe[1], fenc(mny)); atomicMin(&bbe[2], fenc(mnz));
        atomicMax(&bbe[3], fenc(mxx)); atomicMax(&bbe[4], fenc(mxy)); atomicMax(&bbe[5], fenc(mxz));
    }
}

__device__ __forceinline__ void grid_geom(const u32* bbe, float& mnx, float& mny, float& mnz,
                                          float& hx, float& hy, float& hz) {
    mnx = fdec(bbe[0]); mny = fdec(bbe[1]); mnz = fdec(bbe[2]);
    hx = fmaxf((fdec(bbe[3]) - mnx) * (1.0f / G), 1e-20f);
    hy = fmaxf((fdec(bbe[4]) - mny) * (1.0f / G), 1e-20f);
    hz = fmaxf((fdec(bbe[5]) - mnz) * (1.0f / G), 1e-20f);
}

__device__ __forceinline__ u32 cell_of(const u32* bbe, float x, float y, float z) {
    float mnx, mny, mnz, hx, hy, hz;
    grid_geom(bbe, mnx, mny, mnz, hx, hy, hz);
    const int cx = iclamp((int)((x - mnx) / hx), 0, G-1);
    const int cy = iclamp((int)((y - mny) / hy), 0, G-1);
    const int cz = iclamp((int)((z - mnz) / hz), 0, G-1);
    return (u32)((cz * G + cy) * G + cx);
}

__global__ __launch_bounds__(256) void cellid_hist(const float* __restrict__ data,
                                                   const u32* __restrict__ bbe,
                                                   u32* __restrict__ hist) {
    const int i = blockIdx.x * 256 + threadIdx.x;
    atomicAdd(&hist[cell_of(bbe, data[3*i], data[3*i+1], data[3*i+2])], 1u);
}

// ---- parallel 3-kernel scan over G3 cells ----
__global__ __launch_bounds__(256) void scan_partial(const u32* __restrict__ hist,
                                                    u32* __restrict__ cstart,
                                                    u32* __restrict__ bsum) {
    __shared__ u32 lds[256];
    const int t = threadIdx.x;
    const int i = blockIdx.x * 256 + t;
    const u32 v = (i < G3) ? hist[i] : 0u;
    lds[t] = v;
    __syncthreads();
    u32 x = v;
    for (int off = 1; off < 256; off *= 2) {
        const u32 add = (t >= off) ? lds[t - off] : 0u;
        __syncthreads();
        x += add; lds[t] = x;
        __syncthreads();
    }
    if (i < G3) cstart[i] = x - v;                    // block-local exclusive
    if (t == 255) bsum[blockIdx.x] = x;               // block total
}

__global__ __launch_bounds__(256) void scan_bsums(u32* __restrict__ bsum) {
    __shared__ u32 lds[256];
    const int t = threadIdx.x;
    const u32 v = (t < SCB) ? bsum[t] : 0u;
    lds[t] = v;
    __syncthreads();
    u32 x = v;
    for (int off = 1; off < 256; off *= 2) {
        const u32 add = (t >= off) ? lds[t - off] : 0u;
        __syncthreads();
        x += add; lds[t] = x;
        __syncthreads();
    }
    if (t < SCB) bsum[t] = x - v;                     // exclusive block offsets
}

__global__ __launch_bounds__(256) void scan_add(u32* __restrict__ cstart,
                                                u32* __restrict__ cursor,
                                                const u32* __restrict__ bsum) {
    const int i = blockIdx.x * 256 + threadIdx.x;
    if (i < G3) {
        const u32 val = cstart[i] + bsum[blockIdx.x];
        cstart[i] = val; cursor[i] = val;
    }
    if (i == 0) cstart[G3] = (u32)ND;                 // all ND points are binned
}

// pts = (x, y, z, bitcast(original idx)) — one 16B load per candidate
__global__ __launch_bounds__(256) void scatter(const float* __restrict__ data,
                                               const u32* __restrict__ bbe,
                                               u32* __restrict__ cursor,
                                               float4* __restrict__ pts) {
    const int i = blockIdx.x * 256 + threadIdx.x;
    const float x = data[3*i], y = data[3*i+1], z = data[3*i+2];
    const u32 pos = atomicAdd(&cursor[cell_of(bbe, x, y, z)], 1u);
    pts[pos] = make_float4(x, y, z, __uint_as_float((u32)i));
}

// ---------- main query kernel: one wave per query (R6-proven, unchanged) ----------
__global__ __launch_bounds__(256) void knn_grid(const float4* __restrict__ pts,
                                                const u32* __restrict__ cstart,
                                                const float* __restrict__ queries,
                                                const u32* __restrict__ bbe,
                                                int* __restrict__ out_nb,
                                                int* __restrict__ splits) {
    __shared__ float keyP[NWQ][CAP];
    __shared__ u32   idxP[NWQ][CAP];
    __shared__ int   accI[NWQ][KNB];

    const int lane = threadIdx.x & 63;
    const int wid  = threadIdx.x >> 6;
    const int q = blockIdx.x * NWQ + wid;
    const u64 lt = (1ull << lane) - 1ull;
    float* kp = keyP[wid];
    u32*   ip = idxP[wid];

    const float qx = queries[3*q], qy = queries[3*q+1], qz = queries[3*q+2];
    const float q2 = __fadd_rn(__fadd_rn(__fmul_rn(qx,qx), __fmul_rn(qy,qy)), __fmul_rn(qz,qz));

    float mnx, mny, mnz, hx, hy, hz;
    grid_geom(bbe, mnx, mny, mnz, hx, hy, hz);
    const float hmin = fminf(hx, fminf(hy, hz));
    const int cx = iclamp((int)((qx - mnx) / hx), 0, G-1);
    const int cy = iclamp((int)((qy - mny) / hy), 0, G-1);
    const int cz = iclamp((int)((qz - mnz) / hz), 0, G-1);

    float Tk = FINF;
    int cnt = 0;

    auto gather_batch = [&](int sA, int lA, int sB, int lB) {
        const int len = lA + lB;
        const int P = wave_excl_prefix(len, lane);
        const int T = __shfl(P + len, 63, 64);
        #pragma unroll 1
        for (int g0 = 0; g0 < T; g0 += 64) {
            const int pos = g0 + lane;
            const bool val = pos < T;
            int rsel = 0;
            #pragma unroll
            for (int st = 32; st >= 1; st >>= 1) {
                const int t = rsel + st;
                const int Pt = __shfl(P, t, 64);
                if (Pt <= pos) rsel = t;
            }
            const int Pr  = __shfl(P,  rsel, 64);
            const int sAr = __shfl(sA, rsel, 64);
            const int lAr = __shfl(lA, rsel, 64);
            const int sBr = __shfl(sB, rsel, 64);
            const int off = pos - Pr;
            const int pi = (off < lAr) ? (sAr + off) : (sBr + (off - lAr));
            float key = FINF; u32 oi = 0; bool acc = false;
            if (val) {
                const float4 w = pts[pi];
                oi = __float_as_uint(w.w);
                const float d2 = __fadd_rn(__fadd_rn(__fmul_rn(w.x,w.x), __fmul_rn(w.y,w.y)),
                                           __fmul_rn(w.z,w.z));
                const float dot = __fmaf_rn(qz, w.z, __fmaf_rn(qy, w.y, __fmul_rn(qx, w.x)));
                const float sq  = __fsub_rn(__fadd_rn(q2, d2), __fadd_rn(dot, dot));
                key = fmaxf(sq, 0.0f);
                acc = key <= Tk;
            }
            const u64 mask = __ballot(acc);
            if (mask) {
                if (acc) {
                    const int s = cnt + (int)__popcll(mask & lt);
                    kp[s] = key; ip[s] = oi;
                }
                cnt += (int)__popcll(mask);
                if (cnt > CAP - 64) {
                    pool_prune(kp, ip, cnt, Tk, lane, lt);
                    if (cnt > CAP - 64) pool_hard_prune(kp, ip, cnt, lane, lt);
                }
            }
        }
    };

    // Phase A: smallest cube half-width W (cells) with >= KK points
    int W = 0;
    {
        int ccount = 0;
        while (ccount < KK && W < G) {
            ++W;
            const int side = 2*W + 1, nrows = side * side;
            ccount = 0;
            for (int r0 = 0; r0 < nrows; r0 += 64) {
                const int rid = r0 + lane;
                int len = 0;
                if (rid < nrows) {
                    const int dz = rid / side - W, dy = rid % side - W;
                    const int zz = cz + dz, yy = cy + dy;
                    if (zz >= 0 && zz < G && yy >= 0 && yy < G) {
                        const int xlo = cx - W < 0 ? 0 : cx - W;
                        const int xhi = cx + W > G-1 ? G-1 : cx + W;
                        const int rb = (zz * G + yy) * G;
                        len = (int)cstart[rb + xhi + 1] - (int)cstart[rb + xlo];
                    }
                }
                ccount += wave_sum_small<6>(len < 63 ? len : 63);
            }
        }
    }

    // Phase B1: dense gather of cube-W
    {
        const int side = 2*W + 1, nrows = side * side;
        for (int r0 = 0; r0 < nrows; r0 += 64) {
            const int rid = r0 + lane;
            int sA = 0, lA = 0;
            if (rid < nrows) {
                const int dz = rid / side - W, dy = rid % side - W;
                const int zz = cz + dz, yy = cy + dy;
                if (zz >= 0 && zz < G && yy >= 0 && yy < G) {
                    const int xlo = cx - W < 0 ? 0 : cx - W;
                    const int xhi = cx + W > G-1 ? G-1 : cx + W;
                    const int rb = (zz * G + yy) * G;
                    sA = (int)cstart[rb + xlo];
                    lA = (int)cstart[rb + xhi + 1] - sA;
                }
            }
            gather_batch(sA, lA, 0, 0);
        }
    }

    // exact 33rd of cube multiset
    float k33b;
    if (cnt <= 64) {
        float v = (lane < cnt) ? kp[lane] : FINF;
        #pragma unroll
        for (int k = 2; k <= 64; k <<= 1) {
            #pragma unroll
            for (int j = k >> 1; j >= 1; j >>= 1) {
                const float o = __shfl_xor(v, j, 64);
                const bool up = ((lane & k) == 0);
                const bool keepmin = (((lane & j) == 0) == up);
                v = keepmin ? fminf(v, o) : fmaxf(v, o);
            }
        }
        k33b = __shfl(v, KK - 1, 64);
    } else {
        float r[NRR];
        #pragma unroll
        for (int j = 0; j < NRR; ++j) {
            const int s = j * 64 + lane;
            r[j] = (s < cnt) ? kp[s] : FINF;
        }
        k33b = bisect_rank8(r, KK);
    }

    // compact pool to keys <= k33b, tighten Tk
    {
        int nc = 0;
        #pragma unroll 1
        for (int j0 = 0; j0 < cnt; j0 += 64) {
            const int j = j0 + lane;
            const bool val = j < cnt;
            float k = FINF; u32 id = 0;
            if (val) { k = kp[j]; id = ip[j]; }
            const bool keep = val && (k <= k33b);
            const u64 mask = __ballot(keep);
            if (keep) {
                const int s = nc + (int)__popcll(mask & lt);
                kp[s] = k; ip[s] = id;
            }
            nc += (int)__popcll(mask);
        }
        cnt = nc; Tk = k33b;
    }

    // Phase B2: ring gather (ball minus cube) if ball(R2m) escapes cube-W
    const float R2m = __fmaf_rn(k33b, 1.0002f, 1e-3f);
    if (!(R2m < (float)W * (float)W * hmin * hmin)) {
        const float Rm = sqrtf(R2m);
        const int Dz = (int)fminf(floorf(Rm / hz) + 1.0f, (float)G);
        const int Dy = (int)fminf(floorf(Rm / hy) + 1.0f, (float)G);
        const int sidey = 2*Dy + 1;
        const int nrows = (2*Dz + 1) * sidey;
        for (int r0 = 0; r0 < nrows; r0 += 64) {
            const int rid = r0 + lane;
            int sA = 0, lA = 0, sB = 0, lB = 0;
            if (rid < nrows) {
                const int dz = rid / sidey - Dz;
                const int dy = rid % sidey - Dy;
                const int zz = cz + dz, yy = cy + dy;
                if (zz >= 0 && zz < G && yy >= 0 && yy < G) {
                    const int adz = dz < 0 ? -dz : dz;
                    const int ady = dy < 0 ? -dy : dy;
                    const float mz = (adz >= 1) ? (float)(adz - 1) * hz : 0.0f;
                    const float my = (ady >= 1) ? (float)(ady - 1) * hy : 0.0f;
                    const float rowmin2 = mz*mz + my*my;
                    if (rowmin2 <= R2m) {
                        const int dxr = (int)fminf(floorf(sqrtf(R2m - rowmin2) / hx) + 1.0f, (float)G);
                        const int xlo = cx - dxr < 0 ? 0 : cx - dxr;
                        const int xhi = cx + dxr > G-1 ? G-1 : cx + dxr;
                        if (xlo <= xhi) {
                            const int rb = (zz * G + yy) * G;
                            if (adz <= W && ady <= W) {
                                const int xhiA = (cx - W - 1 < xhi) ? cx - W - 1 : xhi;
                                const int xloB = (cx + W + 1 > xlo) ? cx + W + 1 : xlo;
                                if (xlo <= xhiA) {
                                    sA = (int)cstart[rb + xlo];
                                    lA = (int)cstart[rb + xhiA + 1] - sA;
                                }
                                if (xloB <= xhi) {
                                    sB = (int)cstart[rb + xloB];
                                    lB = (int)cstart[rb + xhi + 1] - sB;
                                }
                            } else {
                                sA = (int)cstart[rb + xlo];
                                lA = (int)cstart[rb + xhi + 1] - sA;
                            }
                        }
                    }
                }
            }
            gather_batch(sA, lA, sB, lB);
        }
    }

    // exact global 33rd key
    float k33;
    if (cnt <= 64) {
        float v = (lane < cnt) ? kp[lane] : FINF;
        #pragma unroll
        for (int k = 2; k <= 64; k <<= 1) {
            #pragma unroll
            for (int j = k >> 1; j >= 1; j >>= 1) {
                const float o = __shfl_xor(v, j, 64);
                const bool up = ((lane & k) == 0);
                const bool keepmin = (((lane & j) == 0) == up);
                v = keepmin ? fminf(v, o) : fmaxf(v, o);
            }
        }
        k33 = __shfl(v, KK - 1, 64);
    } else {
        float r[NRR];
        #pragma unroll
        for (int j = 0; j < NRR; ++j) {
            const int s = j * 64 + lane;
            r[j] = (s < cnt) ? kp[s] : FINF;
        }
        k33 = bisect_rank8(r, KK);
    }

    // sqrt-domain cut (R4-proven)
    const float kd = sqrtf(k33);
    float cut;
    if (!(kd > 0.0f)) {
        cut = -1.0f;
    } else {
        int bi = __float_as_int(__fmul_rn(kd, kd));
        #pragma unroll 1
        for (int s = 0; s < 8; ++s) {
            if (bi > 0 && sqrtf(__int_as_float(bi - 1)) >= kd) --bi; else break;
        }
        #pragma unroll 1
        for (int s = 0; s < 8; ++s) {
            if (sqrtf(__int_as_float(bi)) < kd) ++bi; else break;
        }
        cut = __int_as_float(bi);
    }

    // filter pool by key < cut, compact to accI
    int c = 0;
    #pragma unroll 1
    for (int j0 = 0; j0 < cnt; j0 += 64) {
        const int j = j0 + lane;
        const bool val = j < cnt;
        const float k = val ? kp[j] : FINF;
        const bool keep = val && (k < cut);
        const u64 mask = __ballot(keep);
        if (keep) {
            const int s = c + (int)__popcll(mask & lt);
            if (s < KNB) accI[wid][s] = (int)ip[j];
        }
        c += (int)__popcll(mask);
    }
    if (c > KNB) c = KNB;

    // ranking sort by index ascending + padded row write
    if (lane < KNB) {
        if (lane < c) {
            const int my = accI[wid][lane];
            int rank = 0;
            #pragma unroll 1
            for (int j = 0; j < KNB; ++j)
                if (j < c) rank += (accI[wid][j] < my) ? 1 : 0;
            out_nb[(size_t)q * KNB + rank] = my;
        } else {
            out_nb[(size_t)q * KNB + lane] = ND;
        }
    }
    if (lane == 0) splits[1 + q] = c;
}

// --- fallback (ws too small): direct per-thread scan (correct, slow) ---
__global__ __launch_bounds__(256) void knn_direct_kernel(const float* __restrict__ data,
                                                         const float* __restrict__ queries,
                                                         int* __restrict__ out_nb,
                                                         int* __restrict__ splits) {
    __shared__ float4 tile[1024];
    const int q = blockIdx.x * 256 + threadIdx.x;
    const float qx = queries[3*q], qy = queries[3*q+1], qz = queries[3*q+2];
    const float q2 = __fadd_rn(__fadd_rn(__fmul_rn(qx,qx), __fmul_rn(qy,qy)), __fmul_rn(qz,qz));
    float arrk[KK]; int arri[KK];
    for (int j = 0; j < KK; ++j) { arrk[j] = FINF; arri[j] = ND; }
    float cur_maxk = FINF;
    for (int t0 = 0; t0 < ND; t0 += 1024) {
        for (int p = threadIdx.x; p < 1024; p += 256) {
            const int g = t0 + p;
            const float x = data[3*g], y = data[3*g+1], z = data[3*g+2];
            const float d2 = __fadd_rn(__fadd_rn(__fmul_rn(x,x), __fmul_rn(y,y)), __fmul_rn(z,z));
            tile[p] = make_float4(x, y, z, d2);
        }
        __syncthreads();
        for (int p = 0; p < 1024; ++p) {
            const float4 dp = tile[p];
            const float dot = __fmaf_rn(qz, dp.z, __fmaf_rn(qy, dp.y, __fmul_rn(qx, dp.x)));
            const float sq  = __fsub_rn(__fadd_rn(q2, dp.w), __fadd_rn(dot, dot));
            const float key = fmaxf(sq, 0.0f);
            if (key < cur_maxk) {
                int mp = 0; float m = -1.0f;
                for (int j = 0; j < KK; ++j) if (arrk[j] > m) { m = arrk[j]; mp = j; }
                arrk[mp] = key; arri[mp] = t0 + p;
                m = -1.0f;
                for (int j = 0; j < KK; ++j) if (arrk[j] > m) m = arrk[j];
                cur_maxk = m;
            }
        }
        __syncthreads();
    }
    const float kdist = sqrtf(cur_maxk);
    int acc[KNB]; int c = 0;
    for (int j = 0; j < KK; ++j) {
        const float d = sqrtf(arrk[j]);
        if (d < kdist && c < KNB) acc[c++] = arri[j];
    }
    for (int a = 1; a < c; ++a) {
        const int v = acc[a]; int j = a;
        while (j > 0 && acc[j-1] > v) { acc[j] = acc[j-1]; --j; }
        acc[j] = v;
    }
    int* row = out_nb + (size_t)q * KNB;
    for (int j = 0; j < KNB; ++j) row[j] = (j < c) ? acc[j] : ND;
    splits[1 + q] = c;
}

// --- splits: in-place scan of counts (single block) ---
__global__ __launch_bounds__(1024) void splits_scan_kernel(int* __restrict__ splits) {
    __shared__ int lds[1024];
    const int t = threadIdx.x;
    int v[16]; int s = 0;
    #pragma unroll
    for (int j = 0; j < 16; ++j) { v[j] = splits[1 + t*16 + j]; s += v[j]; }
    lds[t] = s;
    __syncthreads();
    for (int off = 1; off < 1024; off *= 2) {
        const int add = (t >= off) ? lds[t - off] : 0;
        __syncthreads();
        lds[t] += add;
        __syncthreads();
    }
    int run = lds[t] - s;
    #pragma unroll
    for (int j = 0; j < 16; ++j) { run += v[j]; splits[1 + t*16 + j] = run; }
    if (t == 0) splits[0] = 0;
}

extern "C" void kernel_launch(void* const* d_in, const int* in_sizes, int n_in,
                              void* d_out, int out_size, void* d_ws, size_t ws_size,
                              hipStream_t stream) {
    const float* data    = (const float*)d_in[0];
    const float* queries = (const float*)d_in[1];
    int* out    = (int*)d_out;
    int* splits = out + SPLITS_BASE;

    // ws layout
    const size_t bb_off     = 0;                                   // 6 u32 (pad 64)
    const size_t hist_off   = 64;
    const size_t cstart_off = hist_off + (size_t)G3 * 4;
    const size_t cursor_off = cstart_off + (size_t)(G3 + 1) * 4;
    const size_t bsum_off   = cursor_off + (size_t)G3 * 4;         // 256 u32
    size_t pts_off          = bsum_off + 256 * 4;
    pts_off = (pts_off + 255) & ~(size_t)255;
    const size_t need       = pts_off + (size_t)ND * 16;           // ~820 KB

    if (ws_size >= need) {
        u32*    bbe    = (u32*)((char*)d_ws + bb_off);
        u32*    hist   = (u32*)((char*)d_ws + hist_off);
        u32*    cstart = (u32*)((char*)d_ws + cstart_off);
        u32*    cursor = (u32*)((char*)d_ws + cursor_off);
        u32*    bsum   = (u32*)((char*)d_ws + bsum_off);
        float4* pts    = (float4*)((char*)d_ws + pts_off);

        hipMemsetAsync(bbe, 0xFF, 12, stream);                     // encoded mins = UINT_MAX
        hipMemsetAsync((char*)bbe + 12, 0x00, 12, stream);         // encoded maxs = 0
        hipMemsetAsync(hist, 0x00, (size_t)G3 * 4, stream);
        hipLaunchKernelGGL(bbox_kernel, dim3(ND / 256), dim3(256), 0, stream, data, bbe);
        hipLaunchKernelGGL(cellid_hist, dim3(ND / 256), dim3(256), 0, stream, data, bbe, hist);
        hipLaunchKernelGGL(scan_partial, dim3(SCB), dim3(256), 0, stream, hist, cstart, bsum);
        hipLaunchKernelGGL(scan_bsums, dim3(1), dim3(256), 0, stream, bsum);
        hipLaunchKernelGGL(scan_add, dim3(SCB), dim3(256), 0, stream, cstart, cursor, bsum);
        hipLaunchKernelGGL(scatter, dim3(ND / 256), dim3(256), 0, stream, data, bbe, cursor, pts);
        hipLaunchKernelGGL(knn_grid, dim3(NQ / NWQ), dim3(256), 0, stream,
                           pts, cstart, queries, bbe, out, splits);
    } else {
        hipLaunchKernelGGL(knn_direct_kernel, dim3(NQ / 256), dim3(256), 0, stream,
                           data, queries, out, splits);
    }
    hipLaunchKernelGGL(splits_scan_kernel, dim3(1), dim3(1024), 0, stream, splits);
}